// Round 1
// baseline (52.512 us; speedup 1.0000x reference)
//
#include <hip/hip_runtime.h>
#include <hip/hip_fp16.h>

// Problem constants (from setup_inputs): L=8, H=32, M=8192, R=16, D=128, S=4096
constexpr int H = 32;
constexpr int S = 4096;
constexpr int D = 128;
constexpr float EPSF = 1e-12f;

// Kernel 1: per (side, head) compute f16-rounded normalized LAST row.
// lastn layout: [2][H][D] f32 (values already rounded through f16).
__global__ void VLKV_lastn_kernel(const float* __restrict__ K,
                                  const float* __restrict__ V,
                                  float* __restrict__ lastn) {
    const int bid  = blockIdx.x;          // 0 .. 2*H-1
    const int side = bid >> 5;            // H == 32
    const int lane = threadIdx.x;         // 64 threads (one wave)
    const int h    = bid & (H - 1);
    const float* src = (side == 0 ? K : V) + ((size_t)h * S + (S - 1)) * D;

    float2 v = *(const float2*)(src + lane * 2);
    float ss = v.x * v.x + v.y * v.y;
#pragma unroll
    for (int m = 1; m < 64; m <<= 1) ss += __shfl_xor(ss, m);
    const float inv = 1.0f / (sqrtf(ss) + EPSF);

    float2 o;
    o.x = __half2float(__float2half(v.x * inv));
    o.y = __half2float(__float2half(v.y * inv));
    *(float2*)(lastn + (size_t)bid * D + lane * 2) = o;
}

// Kernel 2: out[side,h,s,d] = f32(f16(norm(row))) * lastn[side,h,d]
// One 32-lane half-wave per row; float4 per lane (128 floats per row).
__global__ void VLKV_recon_kernel(const float* __restrict__ K,
                                  const float* __restrict__ V,
                                  const float* __restrict__ lastn,
                                  float* __restrict__ out) {
    const int tid  = threadIdx.x;
    const int lane = tid & 63;
    const int wv   = tid >> 6;            // wave index in block
    const int half = lane >> 5;           // which of the 2 rows this wave handles
    const int li   = lane & 31;           // lane within the 32-lane row group
    const int wpb  = blockDim.x >> 6;     // waves per block

    const long nwaves = (long)gridDim.x * wpb;
    const long npairs = (long)H * S;      // (2*H*S rows) / 2 rows-per-wave = 131072

    for (long rp = (long)blockIdx.x * wpb + wv; rp < npairs; rp += nwaves) {
        const long row  = rp * 2 + half;             // global row in [0, 2*H*S)
        const int  side = (int)(row >> 17);          // H*S = 131072 = 2^17
        const long srow = row & (long)(H * S - 1);   // row within the side

        const float* src = (side == 0 ? K : V) + srow * (long)D + li * 4;
        const float4 x = *(const float4*)src;
        float ss = x.x * x.x + x.y * x.y + x.z * x.z + x.w * x.w;
#pragma unroll
        for (int m = 1; m < 32; m <<= 1) ss += __shfl_xor(ss, m);  // stays within 32-lane half

        const float nh = __half2float(__float2half(sqrtf(ss)));

        // row >> 12 == side*H + h  (S = 4096 = 2^12)
        const float4 ln = *(const float4*)(lastn + (row >> 12) * (long)D + li * 4);

        float4 o;
        o.x = nh * ln.x;
        o.y = nh * ln.y;
        o.z = nh * ln.z;
        o.w = nh * ln.w;
        *(float4*)(out + row * (long)D + li * 4) = o;
    }
}

extern "C" void kernel_launch(void* const* d_in, const int* in_sizes, int n_in,
                              void* d_out, int out_size, void* d_ws, size_t ws_size,
                              hipStream_t stream) {
    const float* K = (const float*)d_in[0];   // key_states   [1,H,S,D] f32
    const float* V = (const float*)d_in[1];   // value_states [1,H,S,D] f32
    float* out   = (float*)d_out;             // [2][H][S][D] f32 (k_full ++ v_full)
    float* lastn = (float*)d_ws;              // 2*H*D f32 = 32 KB scratch

    VLKV_lastn_kernel<<<2 * H, 64, 0, stream>>>(K, V, lastn);
    VLKV_recon_kernel<<<2048, 256, 0, stream>>>(K, V, lastn, out);
}

// Round 3
// 52.055 us; speedup vs baseline: 1.0088x; 1.0088x over previous
//
#include <hip/hip_runtime.h>
#include <hip/hip_fp16.h>

// Problem constants (from setup_inputs): L=8, H=32, M=8192, R=16, D=128, S=4096
constexpr int H = 32;
constexpr int S = 4096;
constexpr int D = 128;
constexpr float EPSF = 1e-12f;

typedef float vfloat4 __attribute__((ext_vector_type(4)));

// Kernel 1: per (side, head) compute f16-rounded normalized LAST row.
// lastn layout: [2][H][D] f32 (values already rounded through f16).
__global__ void VLKV_lastn_kernel(const float* __restrict__ K,
                                  const float* __restrict__ V,
                                  float* __restrict__ lastn) {
    const int bid  = blockIdx.x;          // 0 .. 2*H-1
    const int side = bid >> 5;            // H == 32
    const int lane = threadIdx.x;         // 64 threads (one wave)
    const int h    = bid & (H - 1);
    const float* src = (side == 0 ? K : V) + ((size_t)h * S + (S - 1)) * D;

    float2 v = *(const float2*)(src + lane * 2);
    float ss = v.x * v.x + v.y * v.y;
#pragma unroll
    for (int m = 1; m < 64; m <<= 1) ss += __shfl_xor(ss, m);
    const float inv = 1.0f / (sqrtf(ss) + EPSF);

    float2 o;
    o.x = __half2float(__float2half(v.x * inv));
    o.y = __half2float(__float2half(v.y * inv));
    *(float2*)(lastn + (size_t)bid * D + lane * 2) = o;
}

// Kernel 2: out[side,h,s,d] = f32(f16(norm(row))) * lastn[side,h,d]
// One 32-lane half-wave per row; float4 per lane (128 floats per row).
// Output stores are NONTEMPORAL so the 128 MiB of writes don't evict the
// 128 MiB read-only input set from the 256 MiB Infinity Cache.
__global__ void VLKV_recon_kernel(const float* __restrict__ K,
                                  const float* __restrict__ V,
                                  const float* __restrict__ lastn,
                                  float* __restrict__ out) {
    const int tid  = threadIdx.x;
    const int lane = tid & 63;
    const int wv   = tid >> 6;            // wave index in block
    const int half = lane >> 5;           // which of the 2 rows this wave handles
    const int li   = lane & 31;           // lane within the 32-lane row group
    const int wpb  = blockDim.x >> 6;     // waves per block

    const long nwaves = (long)gridDim.x * wpb;
    const long npairs = (long)H * S;      // (2*H*S rows) / 2 rows-per-wave = 131072

    for (long rp = (long)blockIdx.x * wpb + wv; rp < npairs; rp += nwaves) {
        const long row  = rp * 2 + half;             // global row in [0, 2*H*S)
        const int  side = (int)(row >> 17);          // H*S = 131072 = 2^17
        const long srow = row & (long)(H * S - 1);   // row within the side

        const float* src = (side == 0 ? K : V) + srow * (long)D + li * 4;
        const float4 x = *(const float4*)src;
        float ss = x.x * x.x + x.y * x.y + x.z * x.z + x.w * x.w;
#pragma unroll
        for (int m = 1; m < 32; m <<= 1) ss += __shfl_xor(ss, m);  // stays within 32-lane half

        const float nh = __half2float(__float2half(sqrtf(ss)));

        // row >> 12 == side*H + h  (S = 4096 = 2^12)
        const float4 ln = *(const float4*)(lastn + (row >> 12) * (long)D + li * 4);

        vfloat4 o;
        o.x = nh * ln.x;
        o.y = nh * ln.y;
        o.z = nh * ln.z;
        o.w = nh * ln.w;
        __builtin_nontemporal_store(o, (vfloat4*)(out + row * (long)D + li * 4));
    }
}

extern "C" void kernel_launch(void* const* d_in, const int* in_sizes, int n_in,
                              void* d_out, int out_size, void* d_ws, size_t ws_size,
                              hipStream_t stream) {
    const float* K = (const float*)d_in[0];   // key_states   [1,H,S,D] f32
    const float* V = (const float*)d_in[1];   // value_states [1,H,S,D] f32
    float* out   = (float*)d_out;             // [2][H][S][D] f32 (k_full ++ v_full)
    float* lastn = (float*)d_ws;              // 2*H*D f32 = 32 KB scratch

    VLKV_lastn_kernel<<<2 * H, 64, 0, stream>>>(K, V, lastn);
    VLKV_recon_kernel<<<2048, 256, 0, stream>>>(K, V, lastn, out);
}

// Round 4
// 44.809 us; speedup vs baseline: 1.1719x; 1.1617x over previous
//
#include <hip/hip_runtime.h>
#include <hip/hip_fp16.h>

// Problem constants (from setup_inputs): L=8, H=32, M=8192, R=16, D=128, S=4096
constexpr int H = 32;
constexpr int S = 4096;
constexpr int D = 128;
constexpr float EPSF = 1e-12f;

typedef float vfloat4 __attribute__((ext_vector_type(4)));

// Fused single kernel.
// out[side,h,s,d] = f32(f16(||row(side,h,s)||)) * f32(f16(row(side,h,S-1,d)/(||row(side,h,S-1)||+eps)))
//
// Wave decomposition: wave w owns rows [w*32, w*32+32) of the 2*H*S = 262144
// global rows. 32 | S=4096, so all 32 rows share one (side, head). Each
// 32-lane half-wave computes the head's f16-rounded normalized last row ONCE
// into registers, then streams 16 rows: contiguous 16 KB read + 16 KB write
// per wave. No second kernel, no lastn table, no workspace.
__global__ void VLKV_fused_kernel(const float* __restrict__ K,
                                  const float* __restrict__ V,
                                  float* __restrict__ out) {
    const int tid  = threadIdx.x;
    const int lane = tid & 63;
    const int wv   = tid >> 6;            // wave index in block
    const int half = lane >> 5;           // which row of each pair
    const int li   = lane & 31;           // lane within the 32-lane row group

    const long w    = (long)blockIdx.x * (blockDim.x >> 6) + wv;
    const long row0 = w * 32;                       // first global row of this wave
    const int  side = (int)(row0 >> 17);            // H*S = 2^17
    const long srow0 = row0 & (long)(H * S - 1);    // row within side
    const int  h    = (int)(srow0 >> 12);           // head (S = 2^12)

    const float* base = (side == 0 ? K : V);

    // ---- startup: f16-rounded normalized last row of this head, in registers ----
    const float4 lv = *(const float4*)(base + ((long)h * S + (S - 1)) * D + li * 4);
    float lss = lv.x * lv.x + lv.y * lv.y + lv.z * lv.z + lv.w * lv.w;
#pragma unroll
    for (int m = 1; m < 32; m <<= 1) lss += __shfl_xor(lss, m);   // within 32-lane half
    const float inv = 1.0f / (sqrtf(lss) + EPSF);
    float4 ln;
    ln.x = __half2float(__float2half(lv.x * inv));
    ln.y = __half2float(__float2half(lv.y * inv));
    ln.z = __half2float(__float2half(lv.z * inv));
    ln.w = __half2float(__float2half(lv.w * inv));

    // ---- main loop: 16 row-pairs, contiguous streams ----
    const float* src = base + (srow0 + half) * (long)D + li * 4;
    float*       dst = out  + (row0  + half) * (long)D + li * 4;

#pragma unroll 4
    for (int i = 0; i < 16; ++i) {
        const float4 x = *(const float4*)(src + (long)i * 2 * D);
        float ss = x.x * x.x + x.y * x.y + x.z * x.z + x.w * x.w;
#pragma unroll
        for (int m = 1; m < 32; m <<= 1) ss += __shfl_xor(ss, m);
        const float nh = __half2float(__float2half(sqrtf(ss)));

        vfloat4 o;
        o.x = nh * ln.x;
        o.y = nh * ln.y;
        o.z = nh * ln.z;
        o.w = nh * ln.w;
        __builtin_nontemporal_store(o, (vfloat4*)(dst + (long)i * 2 * D));
    }
}

extern "C" void kernel_launch(void* const* d_in, const int* in_sizes, int n_in,
                              void* d_out, int out_size, void* d_ws, size_t ws_size,
                              hipStream_t stream) {
    const float* K = (const float*)d_in[0];   // key_states   [1,H,S,D] f32
    const float* V = (const float*)d_in[1];   // value_states [1,H,S,D] f32
    float* out = (float*)d_out;               // [2][H][S][D] f32 (k_full ++ v_full)

    // 8192 waves × 32 rows/wave = 262144 rows = 2*H*S, exact cover.
    VLKV_fused_kernel<<<2048, 256, 0, stream>>>(K, V, out);
}